// Round 12
// baseline (418.116 us; speedup 1.0000x reference)
//
#include <hip/hip_runtime.h>
#include <math.h>

typedef __bf16 bf16_t;
typedef __bf16 bf16x8 __attribute__((ext_vector_type(8)));
typedef __bf16 bf16x4 __attribute__((ext_vector_type(4)));
typedef float  f32x4  __attribute__((ext_vector_type(4)));

#define NHEAD 16
#define HDIM 64
#define DMODEL 1024
#define TSEQ 2048
#define WEL (DMODEL * DMODEL)

#define SBAR() __builtin_amdgcn_s_barrier()
#define SCHED0() __builtin_amdgcn_sched_barrier(0)
#define LGKM0() do { asm volatile("s_waitcnt lgkmcnt(0)" ::: "memory"); \
                     __builtin_amdgcn_sched_barrier(0); } while (0)

__device__ __forceinline__ f32x4 mfma16(bf16x8 a, bf16x8 b, f32x4 c) {
  return __builtin_amdgcn_mfma_f32_16x16x32_bf16(a, b, c, 0, 0, 0);
}

__device__ __forceinline__ void gload16(const bf16_t* g, bf16_t* l) {
  __builtin_amdgcn_global_load_lds((const __attribute__((address_space(1))) void*)g,
                                   (__attribute__((address_space(3))) void*)l, 16, 0, 0);
}

__device__ __forceinline__ unsigned pk2(float lo, float hi) {
  unsigned short a = __builtin_bit_cast(unsigned short, (__bf16)lo);
  unsigned short c = __builtin_bit_cast(unsigned short, (__bf16)hi);
  return ((unsigned)c << 16) | a;
}

__device__ __forceinline__ void cvtstore(f32x4 x0, f32x4 x1, bf16_t* dh, bf16_t* dl, int off) {
  bf16x8 hfr, lfr;
#pragma unroll
  for (int j = 0; j < 4; ++j) {
    float v = x0[j];
    __bf16 hb = (__bf16)v;
    hfr[j] = hb; lfr[j] = (__bf16)(v - (float)hb);
    float w = x1[j];
    __bf16 wb = (__bf16)w;
    hfr[4 + j] = wb; lfr[4 + j] = (__bf16)(w - (float)wb);
  }
  *(bf16x8*)(dh + off) = hfr;
  *(bf16x8*)(dl + off) = lfr;
}

// ---------------- presplit 4 weight matrices -> hi/lo bf16 ----------------
__global__ __launch_bounds__(256)
void presplit_w(const float* __restrict__ w0, const float* __restrict__ w1,
                const float* __restrict__ w2, const float* __restrict__ w3,
                bf16_t* __restrict__ out) {
  const int y = blockIdx.y;
  const float* src = (y == 0) ? w0 : (y == 1) ? w1 : (y == 2) ? w2 : w3;
  size_t i = ((size_t)blockIdx.x * 256 + threadIdx.x) * 8;
  f32x4 a = *(const f32x4*)(src + i);
  f32x4 c = *(const f32x4*)(src + i + 4);
  bf16x8 h, l;
#pragma unroll
  for (int j = 0; j < 4; ++j) {
    __bf16 hb = (__bf16)a[j];
    h[j] = hb; l[j] = (__bf16)(a[j] - (float)hb);
    __bf16 cb = (__bf16)c[j];
    h[4 + j] = cb; l[4 + j] = (__bf16)(c[j] - (float)cb);
  }
  bf16_t* dh = out + (size_t)y * 2 * WEL;
  *(bf16x8*)(dh + i) = h;
  *(bf16x8*)(dh + WEL + i) = l;
}

// ---------------- bias table ----------------
__global__ __launch_bounds__(256)
void build_bias(const float* __restrict__ amask, const unsigned char* __restrict__ kpm,
                const float* __restrict__ sf, const float* __restrict__ alpha_p,
                bf16_t* __restrict__ BM) {
  size_t idx = (size_t)blockIdx.x * 256 + threadIdx.x;
  int k8 = (int)(idx & (TSEQ / 8 - 1));
  size_t bq = idx >> 8;
  int b = (int)(bq >> 11);
  int q = (int)(bq & (TSEQ - 1));
  const float sfq = sf[bq];
  const float alpha = *alpha_p;
  const float* sfk = sf + (size_t)b * TSEQ + k8 * 8;
  const float* am  = amask + (size_t)q * TSEQ + k8 * 8;
  const unsigned char* kp = kpm + (size_t)b * TSEQ + k8 * 8;
  bf16x8 o;
#pragma unroll
  for (int j = 0; j < 8; ++j) {
    float df = sfq - sfk[j];
    float v = alpha * copysignf(log1pf(fabsf(df)), df) + am[j];
    if (kp[j]) v = -1.0e30f;
    o[j] = (__bf16)v;
  }
  *(bf16x8*)&BM[idx * 8] = o;
}

// ---------------- QKV projection: tile 256x64, 8 waves (4m x 2n), wave tile 64x32 ----------------
// A f32 -> cvtstore into LDS double-buffer (1 raw barrier/step); W pre-split, read
// FRAG-DIRECT from global into regs (reg-dbuf) -> zero W LDS traffic. LDS reads:
// 8 x b128 per 24 MFMA = 48 FLOP/B (below 128 B/cy LDS ceiling -> MFMA-bound).
template<int MODE>
__global__ __launch_bounds__(512)
void gemm_qkv(const float* __restrict__ A, const bf16_t* __restrict__ Wh,
              const bf16_t* __restrict__ Wl, const float* __restrict__ bias,
              bf16_t* __restrict__ obh, bf16_t* __restrict__ obl) {
  __shared__ bf16_t AH[2][16 * 512], AL[2][16 * 512];  // 64 KiB
  const int tid = threadIdx.x;
  const int lane = tid & 63;
  const int a15 = lane & 15, g = lane >> 4;
  const int wv = tid >> 6, wm = wv >> 1, wn = wv & 1;
  const int m0 = blockIdx.y * 256, n0 = blockIdx.x * 64;
  constexpr int NI = (MODE == 2) ? 2 : 4;
  constexpr int NJ = (MODE == 2) ? 4 : 2;
  f32x4 acc[NI][NJ] = {};

  // A staging: 1024 virtual stagers (tid, tid+512) -> 16 tiles of 16 rows x 32 k
  const int t0 = tid >> 6, l0 = tid & 63;
  const float* pA0 = A + (size_t)(m0 + t0 * 16 + (l0 & 15)) * DMODEL + 8 * (l0 >> 4);
  const float* pA1 = pA0 + (size_t)128 * DMODEL;   // tiles 8-15
  // W frag-direct pointers (per-lane)
  const bf16_t* pWh0 = Wh + (size_t)(n0 + wn * 32 + a15) * DMODEL + 8 * g;
  const bf16_t* pWl0 = Wl + (size_t)(n0 + wn * 32 + a15) * DMODEL + 8 * g;

  // prologue: A(0) regs -> buf0; W(0) regs; A(1) regs
  f32x4 rA0a = *(const f32x4*)pA0, rA0b = *(const f32x4*)(pA0 + 4);
  f32x4 rA1a = *(const f32x4*)pA1, rA1b = *(const f32x4*)(pA1 + 4);
  cvtstore(rA0a, rA0b, AH[0], AL[0], tid * 8);
  cvtstore(rA1a, rA1b, AH[0], AL[0], (tid + 512) * 8);
  bf16x8 whc[2], wlc[2], whn[2], wln[2];
  whc[0] = *(const bf16x8*)(pWh0);
  whc[1] = *(const bf16x8*)(pWh0 + 16 * DMODEL);
  wlc[0] = *(const bf16x8*)(pWl0);
  wlc[1] = *(const bf16x8*)(pWl0 + 16 * DMODEL);
  pA0 += 32; pA1 += 32;
  rA0a = *(const f32x4*)pA0; rA0b = *(const f32x4*)(pA0 + 4);
  rA1a = *(const f32x4*)pA1; rA1b = *(const f32x4*)(pA1 + 4);
  LGKM0();
  SBAR();

  constexpr int NK = DMODEL / 32;
  for (int t = 0; t < NK; ++t) {
    const int cur = t & 1;
    // A-frags from LDS buf cur
    bf16x8 ah[4], al[4];
#pragma unroll
    for (int i = 0; i < 4; ++i) {
      ah[i] = *(const bf16x8*)&AH[cur][(wm * 4 + i) * 512 + lane * 8];
      al[i] = *(const bf16x8*)&AL[cur][(wm * 4 + i) * 512 + lane * 8];
    }
    // W(t+1) frag-direct prefetch (in flight across MFMA + barrier)
    if (t + 1 < NK) {
      const int k = (t + 1) * 32;
      whn[0] = *(const bf16x8*)(pWh0 + k);
      whn[1] = *(const bf16x8*)(pWh0 + 16 * DMODEL + k);
      wln[0] = *(const bf16x8*)(pWl0 + k);
      wln[1] = *(const bf16x8*)(pWl0 + 16 * DMODEL + k);
    }
    SCHED0();
    __builtin_amdgcn_s_setprio(1);
    if (MODE == 2) {
#pragma unroll
      for (int i = 0; i < 2; ++i)
#pragma unroll
        for (int j = 0; j < 4; ++j) {
          acc[i][j] = mfma16(whc[i], ah[j], acc[i][j]);
          acc[i][j] = mfma16(whc[i], al[j], acc[i][j]);
          acc[i][j] = mfma16(wlc[i], ah[j], acc[i][j]);
        }
    } else {
#pragma unroll
      for (int i = 0; i < 4; ++i)
#pragma unroll
        for (int j = 0; j < 2; ++j) {
          acc[i][j] = mfma16(ah[i], whc[j], acc[i][j]);
          acc[i][j] = mfma16(ah[i], wlc[j], acc[i][j]);
          acc[i][j] = mfma16(al[i], whc[j], acc[i][j]);
        }
    }
    __builtin_amdgcn_s_setprio(0);
    SCHED0();
    if (t + 1 < NK) {
      // stage A(t+1) (regs loaded last iter) into buf^1; then prefetch A(t+2)
      cvtstore(rA0a, rA0b, AH[cur ^ 1], AL[cur ^ 1], tid * 8);
      cvtstore(rA1a, rA1b, AH[cur ^ 1], AL[cur ^ 1], (tid + 512) * 8);
      SCHED0();
      if (t + 2 < NK) {
        pA0 += 32; pA1 += 32;
        rA0a = *(const f32x4*)pA0; rA0b = *(const f32x4*)(pA0 + 4);
        rA1a = *(const f32x4*)pA1; rA1b = *(const f32x4*)(pA1 + 4);
      }
      whc[0] = whn[0]; whc[1] = whn[1];
      wlc[0] = wln[0]; wlc[1] = wln[1];
    }
    LGKM0();
    SBAR();
  }

  if (MODE == 1) {
#pragma unroll
    for (int i = 0; i < 4; ++i)
#pragma unroll
      for (int j = 0; j < 2; ++j) {
        int n = n0 + wn * 32 + j * 16 + a15;
        float bs = bias[n];
        int hh = n >> 6, d = n & 63;
#pragma unroll
        for (int r = 0; r < 4; ++r) {
          int m = m0 + wm * 64 + i * 16 + 4 * g + r;
          int bb = m >> 11, t = m & (TSEQ - 1);
          float v = acc[i][j][r] + bs;
          size_t o = (((size_t)(bb * NHEAD + hh)) * TSEQ + t) * HDIM + d;
          __bf16 hb = (__bf16)v;
          obh[o] = hb;
          obl[o] = (__bf16)(v - (float)hb);
        }
      }
  } else {
#pragma unroll
    for (int i = 0; i < 2; ++i)
#pragma unroll
      for (int j = 0; j < 4; ++j) {
        int m = m0 + wm * 64 + j * 16 + a15;
        int bb = m >> 11, t = m & (TSEQ - 1);
#pragma unroll
        for (int r = 0; r < 4; ++r) {
          int n = n0 + wn * 32 + i * 16 + 4 * g + r;
          float v = acc[i][j][r] + bias[n];
          int hh = n >> 6, d = n & 63;
          size_t o = (((size_t)(bb * NHEAD + hh)) * HDIM + d) * TSEQ + t;
          __bf16 hb = (__bf16)v;
          obh[o] = hb;
          obl[o] = (__bf16)(v - (float)hb);
        }
      }
  }
}

// ---------------- O projection: tile 256x64, 8 waves, wave 64x32; A gload16 dbuf, W frag-direct ----------------
__global__ __launch_bounds__(512)
void gemm_out(const bf16_t* __restrict__ Ah, const bf16_t* __restrict__ Al,
              const bf16_t* __restrict__ Wh, const bf16_t* __restrict__ Wl,
              const float* __restrict__ bias, float* __restrict__ of) {
  __shared__ bf16_t AHs[2][16 * 512], ALs[2][16 * 512];  // 64 KiB
  const int tid = threadIdx.x;
  const int lane = tid & 63;
  const int a15 = lane & 15, g = lane >> 4;
  const int wv = tid >> 6, wm = wv >> 1, wn = wv & 1;
  const int m0 = blockIdx.y * 256, n0 = blockIdx.x * 64;
  f32x4 acc[4][2] = {};

  // wave wv stages AH slots {2wv, 2wv+1} + same AL slots (4 gloads/wave/step)
  const bf16_t* pAh0 = Ah + (size_t)(m0 + (2 * wv) * 16 + a15) * DMODEL + 8 * g;
  const bf16_t* pAh1 = Ah + (size_t)(m0 + (2 * wv + 1) * 16 + a15) * DMODEL + 8 * g;
  const bf16_t* pAl0 = Al + (size_t)(m0 + (2 * wv) * 16 + a15) * DMODEL + 8 * g;
  const bf16_t* pAl1 = Al + (size_t)(m0 + (2 * wv + 1) * 16 + a15) * DMODEL + 8 * g;
  const bf16_t* pWh0 = Wh + (size_t)(n0 + wn * 32 + a15) * DMODEL + 8 * g;
  const bf16_t* pWl0 = Wl + (size_t)(n0 + wn * 32 + a15) * DMODEL + 8 * g;

  auto stageA = [&](int t, int buf) {
    gload16(pAh0 + t * 32, &AHs[buf][(2 * wv) * 512]);
    gload16(pAh1 + t * 32, &AHs[buf][(2 * wv + 1) * 512]);
    gload16(pAl0 + t * 32, &ALs[buf][(2 * wv) * 512]);
    gload16(pAl1 + t * 32, &ALs[buf][(2 * wv + 1) * 512]);
  };

  bf16x8 whc[2], wlc[2], whn[2], wln[2];
  stageA(0, 0);
  whc[0] = *(const bf16x8*)(pWh0);
  whc[1] = *(const bf16x8*)(pWh0 + 16 * DMODEL);
  wlc[0] = *(const bf16x8*)(pWl0);
  wlc[1] = *(const bf16x8*)(pWl0 + 16 * DMODEL);

  constexpr int NK = DMODEL / 32;
  for (int t = 0; t < NK; ++t) {
    const int cur = t & 1;
    if (t + 1 < NK) {
      const int k = (t + 1) * 32;
      stageA(t + 1, cur ^ 1);                           // 4 gloads
      whn[0] = *(const bf16x8*)(pWh0 + k);              // 4 reg loads
      whn[1] = *(const bf16x8*)(pWh0 + 16 * DMODEL + k);
      wln[0] = *(const bf16x8*)(pWl0 + k);
      wln[1] = *(const bf16x8*)(pWl0 + 16 * DMODEL + k);
      asm volatile("s_waitcnt vmcnt(8)" ::: "memory");  // drain A(t) gloads + W(t) loads
    } else {
      asm volatile("s_waitcnt vmcnt(0)" ::: "memory");
    }
    SCHED0();
    SBAR();

    bf16x8 ah[4], al[4];
#pragma unroll
    for (int i = 0; i < 4; ++i) {
      ah[i] = *(const bf16x8*)&AHs[cur][(wm * 4 + i) * 512 + lane * 8];
      al[i] = *(const bf16x8*)&ALs[cur][(wm * 4 + i) * 512 + lane * 8];
    }
    __builtin_amdgcn_s_setprio(1);
#pragma unroll
    for (int i = 0; i < 4; ++i)
#pragma unroll
      for (int j = 0; j < 2; ++j) {
        acc[i][j] = mfma16(ah[i], whc[j], acc[i][j]);
        acc[i][j] = mfma16(ah[i], wlc[j], acc[i][j]);
        acc[i][j] = mfma16(al[i], whc[j], acc[i][j]);
      }
    __builtin_amdgcn_s_setprio(0);
    if (t + 1 < NK) {
      whc[0] = whn[0]; whc[1] = whn[1];
      wlc[0] = wln[0]; wlc[1] = wln[1];
    }
    SBAR();   // all waves done reading buf cur before next stage overwrites
  }

#pragma unroll
  for (int i = 0; i < 4; ++i)
#pragma unroll
    for (int j = 0; j < 2; ++j) {
      int n = n0 + wn * 32 + j * 16 + a15;
      float bs = bias[n];
#pragma unroll
      for (int r = 0; r < 4; ++r) {
        int m = m0 + wm * 64 + i * 16 + 4 * g + r;
        of[(size_t)m * DMODEL + n] = acc[i][j][r] + bs;
      }
    }
}

// ---------------- Flash attention (R9/R11 proven config, unchanged) ----------------
__global__ __launch_bounds__(512)
void attn_mfma(const bf16_t* __restrict__ Qhi, const bf16_t* __restrict__ Qlo,
               const bf16_t* __restrict__ Khi, const bf16_t* __restrict__ Klo,
               const bf16_t* __restrict__ Vth, const bf16_t* __restrict__ Vtl,
               const bf16_t* __restrict__ BMt,
               bf16_t* __restrict__ Oh, bf16_t* __restrict__ Ol) {
  __shared__ bf16_t KH[2][8 * 512], KL[2][8 * 512], VH[2][8 * 512], VL[2][8 * 512];
  __shared__ bf16_t PS[8 * 512];
  const int tid = threadIdx.x;
  const int lane = tid & 63, wv = tid >> 6;
  const int a15 = lane & 15, g = lane >> 4;
  const int b = blockIdx.z, h = blockIdx.y, q0 = blockIdx.x * 128;
  const int bh = b * NHEAD + h;
  const int qg = q0 + wv * 16 + a15;
  constexpr int NT = TSEQ / 64;

  const bf16_t* Qh_b = Qhi + ((size_t)bh * TSEQ + qg) * HDIM;
  const bf16_t* Ql_b = Qlo + ((size_t)bh * TSEQ + qg) * HDIM;
  const bf16_t* Kh_b = Khi + (size_t)bh * TSEQ * HDIM;
  const bf16_t* Kl_b = Klo + (size_t)bh * TSEQ * HDIM;
  const bf16_t* Vh_b = Vth + (size_t)bh * HDIM * TSEQ;
  const bf16_t* Vl_b = Vtl + (size_t)bh * HDIM * TSEQ;
  const bf16_t* bmrow = BMt + ((size_t)b * TSEQ + qg) * TSEQ;

  bf16x8 qh[2], ql[2];
  qh[0] = *(const bf16x8*)&Qh_b[8 * g];
  qh[1] = *(const bf16x8*)&Qh_b[32 + 8 * g];
  ql[0] = *(const bf16x8*)&Ql_b[8 * g];
  ql[1] = *(const bf16x8*)&Ql_b[32 + 8 * g];

  f32x4 aco[4] = {};
  float m_run = -3.0e38f, l_run = 0.f;
  bf16x4 bmv[4], bmn[4];

  const int ts = wv >> 1, ks = wv & 1;
  auto stage = [&](int k0, int buf) {
    size_t ko = (size_t)(k0 + 16 * ts + a15) * HDIM + 32 * ks + 8 * g;
    gload16(Kh_b + ko, &KH[buf][wv * 512]);
    gload16(Kl_b + ko, &KL[buf][wv * 512]);
    size_t vo = (size_t)(16 * ts + a15) * TSEQ + k0 + 32 * ks + 8 * g;
    gload16(Vh_b + vo, &VH[buf][wv * 512]);
    gload16(Vl_b + vo, &VL[buf][wv * 512]);
  };

#pragma unroll
  for (int mt = 0; mt < 4; ++mt) bmv[mt] = *(const bf16x4*)&bmrow[16 * mt + 4 * g];
  stage(0, 0);

  const int psb = wv * 512 + a15 * 32;
  const int r3 = a15 & 3;

  for (int t = 0; t < NT; ++t) {
    const int cur = t & 1;
    if (t + 1 < NT) {
      const int kn = (t + 1) * 64;
#pragma unroll
      for (int mt = 0; mt < 4; ++mt) bmn[mt] = *(const bf16x4*)&bmrow[kn + 16 * mt + 4 * g];
      stage(kn, cur ^ 1);
      asm volatile("s_waitcnt vmcnt(8)" ::: "memory");
    } else {
      asm volatile("s_waitcnt vmcnt(0)" ::: "memory");
    }
    SCHED0();
    SBAR();

    f32x4 s4[4];
    __builtin_amdgcn_s_setprio(1);
#pragma unroll
    for (int mt = 0; mt < 4; ++mt) {
      bf16x8 k0h = *(const bf16x8*)&KH[cur][(mt * 2 + 0) * 512 + lane * 8];
      bf16x8 k1h = *(const bf16x8*)&KH[cur][(mt * 2 + 1) * 512 + lane * 8];
      bf16x8 k0l = *(const bf16x8*)&KL[cur][(mt * 2 + 0) * 512 + lane * 8];
      bf16x8 k1l = *(const bf16x8*)&KL[cur][(mt * 2 + 1) * 512 + lane * 8];
      f32x4 sa = {};
      sa = mfma16(k0h, qh[0], sa);
      sa = mfma16(k1h, qh[1], sa);
      sa = mfma16(k0h, ql[0], sa);
      sa = mfma16(k1h, ql[1], sa);
      sa = mfma16(k0l, qh[0], sa);
      sa = mfma16(k1l, qh[1], sa);
      s4[mt] = sa;
    }
    __builtin_amdgcn_s_setprio(0);

#pragma unroll
    for (int mt = 0; mt < 4; ++mt)
#pragma unroll
      for (int r = 0; r < 4; ++r)
        s4[mt][r] = fmaf(s4[mt][r], 0.125f, (float)bmv[mt][r]);

    float tmax = -3.0e38f;
#pragma unroll
    for (int mt = 0; mt < 4; ++mt)
#pragma unroll
      for (int r = 0; r < 4; ++r) tmax = fmaxf(tmax, s4[mt][r]);
    tmax = fmaxf(tmax, __shfl_xor(tmax, 16));
    tmax = fmaxf(tmax, __shfl_xor(tmax, 32));
    if (!__all(tmax - m_run <= 8.0f)) {
      float mnew = fmaxf(m_run, tmax);
      float corr = __expf(m_run - mnew);
      l_run *= corr;
#pragma unroll
      for (int dt = 0; dt < 4; ++dt) aco[dt] *= corr;
      m_run = mnew;
    }
    float psum = 0.f;
    unsigned pk01[4], pk23[4];
#pragma unroll
    for (int mt = 0; mt < 4; ++mt) {
      float p0 = __expf(s4[mt][0] - m_run);
      float p1 = __expf(s4[mt][1] - m_run);
      float p2 = __expf(s4[mt][2] - m_run);
      float p3 = __expf(s4[mt][3] - m_run);
      psum += (p0 + p1) + (p2 + p3);
      pk01[mt] = pk2(p0, p1);
      pk23[mt] = pk2(p2, p3);
    }
    psum += __shfl_xor(psum, 16);
    psum += __shfl_xor(psum, 32);
    l_run += psum;

    __builtin_amdgcn_s_setprio(1);
#pragma unroll
    for (int kss = 0; kss < 2; ++kss) {
#pragma unroll
      for (int mh = 0; mh < 2; ++mh) {
        int mt = kss * 2 + mh;
        int phys = ((mh << 1) | (g >> 1)) ^ r3;
        uint2 w2;
        w2.x = pk01[mt];
        w2.y = pk23[mt];
        *(uint2*)&PS[psb + phys * 8 + (g & 1) * 4] = w2;
      }
      LGKM0();
      bf16x8 pf = *(const bf16x8*)&PS[psb + ((g ^ r3) << 3)];
#pragma unroll
      for (int dt = 0; dt < 4; ++dt) {
        bf16x8 vh = *(const bf16x8*)&VH[cur][(dt * 2 + kss) * 512 + lane * 8];
        bf16x8 vl = *(const bf16x8*)&VL[cur][(dt * 2 + kss) * 512 + lane * 8];
        aco[dt] = mfma16(vh, pf, aco[dt]);
        aco[dt] = mfma16(vl, pf, aco[dt]);
      }
    }
    __builtin_amdgcn_s_setprio(0);

    if (t + 1 < NT) {
#pragma unroll
      for (int mt = 0; mt < 4; ++mt) bmv[mt] = bmn[mt];
    }
    SBAR();
  }

  float inv = 1.0f / l_run;
#pragma unroll
  for (int dt = 0; dt < 4; ++dt) {
    f32x4 o = aco[dt] * inv;
    bf16x4 oh, ol;
#pragma unroll
    for (int r = 0; r < 4; ++r) {
      __bf16 hb = (__bf16)o[r];
      oh[r] = hb;
      ol[r] = (__bf16)(o[r] - (float)hb);
    }
    size_t off = ((size_t)b * TSEQ + qg) * DMODEL + h * HDIM + dt * 16 + 4 * g;
    *(bf16x4*)&Oh[off] = oh;
    *(bf16x4*)&Ol[off] = ol;
  }
}

extern "C" void kernel_launch(void* const* d_in, const int* in_sizes, int n_in,
                              void* d_out, int out_size, void* d_ws, size_t ws_size,
                              hipStream_t stream) {
  const float* query = (const float*)d_in[0];
  const float* key = (const float*)d_in[1];
  const float* value = (const float*)d_in[2];
  const unsigned char* kpm = (const unsigned char*)d_in[3];
  const float* amask = (const float*)d_in[4];
  const float* sf = (const float*)d_in[5];
  const float* Wq = (const float*)d_in[6];
  const float* bq = (const float*)d_in[7];
  const float* Wk = (const float*)d_in[8];
  const float* bk = (const float*)d_in[9];
  const float* Wv = (const float*)d_in[10];
  const float* bv = (const float*)d_in[11];
  const float* Wo = (const float*)d_in[12];
  const float* bo = (const float*)d_in[13];
  const float* alpha = (const float*)d_in[14];
  float* out = (float*)d_out;

  const size_t NEL = (size_t)2 * NHEAD * TSEQ * HDIM;
  bf16_t* p = (bf16_t*)d_ws;
  bf16_t* Qh = p;
  bf16_t* Ql = p + NEL;
  bf16_t* Kh = p + 2 * NEL;
  bf16_t* Kl = p + 3 * NEL;
  bf16_t* Vh = p + 4 * NEL;
  bf16_t* Vl = p + 5 * NEL;
  bf16_t* Oh = p + 6 * NEL;
  bf16_t* Ol = p + 7 * NEL;
  bf16_t* BMt = p + 8 * NEL;
  bf16_t* wsp = p + 10 * NEL;
  bf16_t* wqh = wsp + 0 * WEL, *wql = wsp + 1 * WEL;
  bf16_t* wkh = wsp + 2 * WEL, *wkl = wsp + 3 * WEL;
  bf16_t* wvh = wsp + 4 * WEL, *wvl = wsp + 5 * WEL;
  bf16_t* woh = wsp + 6 * WEL, *wol = wsp + 7 * WEL;

  presplit_w<<<dim3(WEL / (256 * 8), 4), dim3(256), 0, stream>>>(Wq, Wk, Wv, Wo, wsp);
  build_bias<<<dim3(4096), dim3(256), 0, stream>>>(amask, kpm, sf, alpha, BMt);

  dim3 gg(DMODEL / 64, 4096 / 256), gb(512);   // (16, 16) = 256 blocks
  gemm_qkv<1><<<gg, gb, 0, stream>>>(query, wqh, wql, bq, Qh, Ql);
  gemm_qkv<1><<<gg, gb, 0, stream>>>(key, wkh, wkl, bk, Kh, Kl);
  gemm_qkv<2><<<gg, gb, 0, stream>>>(value, wvh, wvl, bv, Vh, Vl);
  dim3 ga(TSEQ / 128, NHEAD, 2);
  attn_mfma<<<ga, gb, 0, stream>>>(Qh, Ql, Kh, Kl, Vh, Vl, BMt, Oh, Ol);
  gemm_out<<<gg, gb, 0, stream>>>(Oh, Ol, woh, wol, bo, out);
}

// Round 13
// 340.330 us; speedup vs baseline: 1.2286x; 1.2286x over previous
//
#include <hip/hip_runtime.h>
#include <math.h>

typedef __bf16 bf16_t;
typedef __bf16 bf16x8 __attribute__((ext_vector_type(8)));
typedef __bf16 bf16x4 __attribute__((ext_vector_type(4)));
typedef float  f32x4  __attribute__((ext_vector_type(4)));

#define NHEAD 16
#define HDIM 64
#define DMODEL 1024
#define TSEQ 2048
#define WEL (DMODEL * DMODEL)

#define SBAR() __builtin_amdgcn_s_barrier()
#define SCHED0() __builtin_amdgcn_sched_barrier(0)
#define LGKM0() do { asm volatile("s_waitcnt lgkmcnt(0)" ::: "memory"); \
                     __builtin_amdgcn_sched_barrier(0); } while (0)

__device__ __forceinline__ f32x4 mfma16(bf16x8 a, bf16x8 b, f32x4 c) {
  return __builtin_amdgcn_mfma_f32_16x16x32_bf16(a, b, c, 0, 0, 0);
}

__device__ __forceinline__ void gload16(const bf16_t* g, bf16_t* l) {
  __builtin_amdgcn_global_load_lds((const __attribute__((address_space(1))) void*)g,
                                   (__attribute__((address_space(3))) void*)l, 16, 0, 0);
}

__device__ __forceinline__ unsigned pk2(float lo, float hi) {
  unsigned short a = __builtin_bit_cast(unsigned short, (__bf16)lo);
  unsigned short c = __builtin_bit_cast(unsigned short, (__bf16)hi);
  return ((unsigned)c << 16) | a;
}

__device__ __forceinline__ void cvtstore(f32x4 x0, f32x4 x1, bf16_t* dh, bf16_t* dl, int off) {
  bf16x8 hfr, lfr;
#pragma unroll
  for (int j = 0; j < 4; ++j) {
    float v = x0[j];
    __bf16 hb = (__bf16)v;
    hfr[j] = hb; lfr[j] = (__bf16)(v - (float)hb);
    float w = x1[j];
    __bf16 wb = (__bf16)w;
    hfr[4 + j] = wb; lfr[4 + j] = (__bf16)(w - (float)wb);
  }
  *(bf16x8*)(dh + off) = hfr;
  *(bf16x8*)(dl + off) = lfr;
}

// ---------------- presplit 4 weight matrices -> hi/lo bf16 ----------------
__global__ __launch_bounds__(256)
void presplit_w(const float* __restrict__ w0, const float* __restrict__ w1,
                const float* __restrict__ w2, const float* __restrict__ w3,
                bf16_t* __restrict__ out) {
  const int y = blockIdx.y;
  const float* src = (y == 0) ? w0 : (y == 1) ? w1 : (y == 2) ? w2 : w3;
  size_t i = ((size_t)blockIdx.x * 256 + threadIdx.x) * 8;
  f32x4 a = *(const f32x4*)(src + i);
  f32x4 c = *(const f32x4*)(src + i + 4);
  bf16x8 h, l;
#pragma unroll
  for (int j = 0; j < 4; ++j) {
    __bf16 hb = (__bf16)a[j];
    h[j] = hb; l[j] = (__bf16)(a[j] - (float)hb);
    __bf16 cb = (__bf16)c[j];
    h[4 + j] = cb; l[4 + j] = (__bf16)(c[j] - (float)cb);
  }
  bf16_t* dh = out + (size_t)y * 2 * WEL;
  *(bf16x8*)(dh + i) = h;
  *(bf16x8*)(dh + WEL + i) = l;
}

// ---------------- bias table ----------------
__global__ __launch_bounds__(256)
void build_bias(const float* __restrict__ amask, const unsigned char* __restrict__ kpm,
                const float* __restrict__ sf, const float* __restrict__ alpha_p,
                bf16_t* __restrict__ BM) {
  size_t idx = (size_t)blockIdx.x * 256 + threadIdx.x;
  int k8 = (int)(idx & (TSEQ / 8 - 1));
  size_t bq = idx >> 8;
  int b = (int)(bq >> 11);
  int q = (int)(bq & (TSEQ - 1));
  const float sfq = sf[bq];
  const float alpha = *alpha_p;
  const float* sfk = sf + (size_t)b * TSEQ + k8 * 8;
  const float* am  = amask + (size_t)q * TSEQ + k8 * 8;
  const unsigned char* kp = kpm + (size_t)b * TSEQ + k8 * 8;
  bf16x8 o;
#pragma unroll
  for (int j = 0; j < 8; ++j) {
    float df = sfq - sfk[j];
    float v = alpha * copysignf(log1pf(fabsf(df)), df) + am[j];
    if (kp[j]) v = -1.0e30f;
    o[j] = (__bf16)v;
  }
  *(bf16x8*)&BM[idx * 8] = o;
}

// ---------------- Fused QKV projection (R11 structure, z selects Q/K/V) ----------------
// 512 thr (8 waves, 4m x 2n of 32x32), tile 128x64, BK=32. A f32 cvtstore in-loop;
// W pre-split, gload16 LDS dbuf, counted vmcnt(3). blockIdx.z = 0/1/2 -> Q/K/V.
// V path (z==2): swapped MFMA operands + transposed [b][h][d][t] epilogue.
__global__ __launch_bounds__(512)
void gemm_qkv_fused(const float* __restrict__ Aq, const float* __restrict__ Ak,
                    const float* __restrict__ Av, const bf16_t* __restrict__ wsp,
                    const float* __restrict__ bq, const float* __restrict__ bk,
                    const float* __restrict__ bv, bf16_t* __restrict__ outbase) {
  __shared__ bf16_t AH[8 * 512], AL[8 * 512], WHs[2][4 * 512], WLs[2][4 * 512];  // 32 KiB
  const int z = blockIdx.z;
  const float* A = (z == 0) ? Aq : (z == 1) ? Ak : Av;
  const bf16_t* Wh = wsp + (size_t)2 * z * WEL;
  const bf16_t* Wl = Wh + WEL;
  const float* bias = (z == 0) ? bq : (z == 1) ? bk : bv;
  const size_t NELq = (size_t)2 * NHEAD * TSEQ * HDIM;
  bf16_t* obh = outbase + (size_t)2 * z * NELq;
  bf16_t* obl = obh + NELq;
  const bool vmode = (z == 2);

  const int tid = threadIdx.x;
  const int lane = tid & 63;
  const int a15 = lane & 15, g = lane >> 4;
  const int wv = tid >> 6, wm = wv >> 1, wn = wv & 1;
  const int m0 = blockIdx.y * 128, n0 = blockIdx.x * 64;
  f32x4 acc[2][2] = {};

  const int t0 = tid >> 6, l0 = tid & 63;
  const float* pA = A + (size_t)(m0 + t0 * 16 + (l0 & 15)) * DMODEL + 8 * (l0 >> 4);
  const int wts = wv & 3;
  const bf16_t* pWg = ((wv < 4) ? Wh : Wl) + (size_t)(n0 + wts * 16 + a15) * DMODEL + 8 * g;

  f32x4 rAa = *(const f32x4*)pA, rAb = *(const f32x4*)(pA + 4);
  gload16(pWg, (wv < 4) ? &WHs[0][wts * 512] : &WLs[0][wts * 512]);

  constexpr int NK = DMODEL / 32;
  for (int t = 0; t < NK; ++t) {
    const int cur = t & 1;
    SBAR();                                   // prior step's LDS reads consumed
    cvtstore(rAa, rAb, AH, AL, tid * 8);      // waits rA only; W(t) stays in flight
    SCHED0();
    if (t + 1 < NK) {
      pA += 32;
      rAa = *(const f32x4*)pA; rAb = *(const f32x4*)(pA + 4);   // A prefetch t+1
      SCHED0();
      gload16(pWg + (t + 1) * 32, (wv < 4) ? &WHs[cur ^ 1][wts * 512]
                                           : &WLs[cur ^ 1][wts * 512]);
      SCHED0();
      asm volatile("s_waitcnt vmcnt(3)" ::: "memory");  // drain W(t); keep rA(t+1)x2 + W(t+1)
    } else {
      asm volatile("s_waitcnt vmcnt(0)" ::: "memory");
    }
    LGKM0();                                  // ds_writes committed
    SBAR();

    bf16x8 ah[2], al[2], wh[2], wl[2];
#pragma unroll
    for (int i = 0; i < 2; ++i) {
      ah[i] = *(const bf16x8*)&AH[(wm * 2 + i) * 512 + lane * 8];
      al[i] = *(const bf16x8*)&AL[(wm * 2 + i) * 512 + lane * 8];
      wh[i] = *(const bf16x8*)&WHs[cur][(wn * 2 + i) * 512 + lane * 8];
      wl[i] = *(const bf16x8*)&WLs[cur][(wn * 2 + i) * 512 + lane * 8];
    }
    __builtin_amdgcn_s_setprio(1);
    if (vmode) {
#pragma unroll
      for (int i = 0; i < 2; ++i)
#pragma unroll
        for (int j = 0; j < 2; ++j) {
          acc[i][j] = mfma16(wh[i], ah[j], acc[i][j]);
          acc[i][j] = mfma16(wh[i], al[j], acc[i][j]);
          acc[i][j] = mfma16(wl[i], ah[j], acc[i][j]);
        }
    } else {
#pragma unroll
      for (int i = 0; i < 2; ++i)
#pragma unroll
        for (int j = 0; j < 2; ++j) {
          acc[i][j] = mfma16(ah[i], wh[j], acc[i][j]);
          acc[i][j] = mfma16(ah[i], wl[j], acc[i][j]);
          acc[i][j] = mfma16(al[i], wh[j], acc[i][j]);
        }
    }
    __builtin_amdgcn_s_setprio(0);
  }

  if (!vmode) {
#pragma unroll
    for (int i = 0; i < 2; ++i)
#pragma unroll
      for (int j = 0; j < 2; ++j) {
        int n = n0 + wn * 32 + j * 16 + a15;
        float bs = bias[n];
        int hh = n >> 6, d = n & 63;
#pragma unroll
        for (int r = 0; r < 4; ++r) {
          int m = m0 + wm * 32 + i * 16 + 4 * g + r;
          int bb = m >> 11, t = m & (TSEQ - 1);
          float v = acc[i][j][r] + bs;
          size_t o = (((size_t)(bb * NHEAD + hh)) * TSEQ + t) * HDIM + d;
          __bf16 hb = (__bf16)v;
          obh[o] = hb;
          obl[o] = (__bf16)(v - (float)hb);
        }
      }
  } else {
    // D rows = W subtile (n-dim, i), D cols = A subtile (m-dim, j)
#pragma unroll
    for (int i = 0; i < 2; ++i)
#pragma unroll
      for (int j = 0; j < 2; ++j) {
        int m = m0 + wm * 32 + j * 16 + a15;
        int bb = m >> 11, t = m & (TSEQ - 1);
#pragma unroll
        for (int r = 0; r < 4; ++r) {
          int n = n0 + wn * 32 + i * 16 + 4 * g + r;
          float v = acc[i][j][r] + bias[n];
          int hh = n >> 6, d = n & 63;
          size_t o = (((size_t)(bb * NHEAD + hh)) * HDIM + d) * TSEQ + t;
          __bf16 hb = (__bf16)v;
          obh[o] = hb;
          obl[o] = (__bf16)(v - (float)hb);
        }
      }
  }
}

// ---------------- O projection: A and W both pre-split bf16, pure gload16 dbuf (R11) ----------------
__global__ __launch_bounds__(512)
void gemm_out(const bf16_t* __restrict__ Ah, const bf16_t* __restrict__ Al,
              const bf16_t* __restrict__ Wh, const bf16_t* __restrict__ Wl,
              const float* __restrict__ bias, float* __restrict__ of) {
  __shared__ bf16_t AHs[2][8 * 512], ALs[2][8 * 512], WHs[2][4 * 512], WLs[2][4 * 512];  // 48 KiB
  const int tid = threadIdx.x;
  const int lane = tid & 63;
  const int a15 = lane & 15, g = lane >> 4;
  const int wv = tid >> 6, wm = wv >> 1, wn = wv & 1;
  const int m0 = blockIdx.y * 128, n0 = blockIdx.x * 64;
  f32x4 acc[2][2] = {};

  const bf16_t* pAh = Ah + (size_t)(m0 + wv * 16 + a15) * DMODEL + 8 * g;
  const bf16_t* pAl = Al + (size_t)(m0 + wv * 16 + a15) * DMODEL + 8 * g;
  const int wts = wv & 3;
  const bf16_t* pWg = ((wv < 4) ? Wh : Wl) + (size_t)(n0 + wts * 16 + a15) * DMODEL + 8 * g;

  auto stage = [&](int t, int buf) {
    gload16(pAh + t * 32, &AHs[buf][wv * 512]);
    gload16(pAl + t * 32, &ALs[buf][wv * 512]);
    gload16(pWg + t * 32, (wv < 4) ? &WHs[buf][wts * 512] : &WLs[buf][wts * 512]);
  };
  stage(0, 0);

  constexpr int NK = DMODEL / 32;
  for (int t = 0; t < NK; ++t) {
    const int cur = t & 1;
    if (t + 1 < NK) {
      stage(t + 1, cur ^ 1);                            // 3 gloads, stay in flight
      asm volatile("s_waitcnt vmcnt(3)" ::: "memory");  // drain tile t's 3 only
    } else {
      asm volatile("s_waitcnt vmcnt(0)" ::: "memory");
    }
    SCHED0();
    SBAR();

    bf16x8 ah[2], al[2], wh[2], wl[2];
#pragma unroll
    for (int i = 0; i < 2; ++i) {
      ah[i] = *(const bf16x8*)&AHs[cur][(wm * 2 + i) * 512 + lane * 8];
      al[i] = *(const bf16x8*)&ALs[cur][(wm * 2 + i) * 512 + lane * 8];
      wh[i] = *(const bf16x8*)&WHs[cur][(wn * 2 + i) * 512 + lane * 8];
      wl[i] = *(const bf16x8*)&WLs[cur][(wn * 2 + i) * 512 + lane * 8];
    }
    __builtin_amdgcn_s_setprio(1);
#pragma unroll
    for (int i = 0; i < 2; ++i)
#pragma unroll
      for (int j = 0; j < 2; ++j) {
        acc[i][j] = mfma16(ah[i], wh[j], acc[i][j]);
        acc[i][j] = mfma16(ah[i], wl[j], acc[i][j]);
        acc[i][j] = mfma16(al[i], wh[j], acc[i][j]);
      }
    __builtin_amdgcn_s_setprio(0);
    SBAR();   // all waves done reading buf cur before next stage overwrites
  }

#pragma unroll
  for (int i = 0; i < 2; ++i)
#pragma unroll
    for (int j = 0; j < 2; ++j) {
      int n = n0 + wn * 32 + j * 16 + a15;
      float bs = bias[n];
#pragma unroll
      for (int r = 0; r < 4; ++r) {
        int m = m0 + wm * 32 + i * 16 + 4 * g + r;
        of[(size_t)m * DMODEL + n] = acc[i][j][r] + bs;
      }
    }
}

// ---------------- Flash attention (R11 config + deferred l-reduction) ----------------
__global__ __launch_bounds__(512)
void attn_mfma(const bf16_t* __restrict__ Qhi, const bf16_t* __restrict__ Qlo,
               const bf16_t* __restrict__ Khi, const bf16_t* __restrict__ Klo,
               const bf16_t* __restrict__ Vth, const bf16_t* __restrict__ Vtl,
               const bf16_t* __restrict__ BMt,
               bf16_t* __restrict__ Oh, bf16_t* __restrict__ Ol) {
  __shared__ bf16_t KH[2][8 * 512], KL[2][8 * 512], VH[2][8 * 512], VL[2][8 * 512];
  __shared__ bf16_t PS[8 * 512];
  const int tid = threadIdx.x;
  const int lane = tid & 63, wv = tid >> 6;
  const int a15 = lane & 15, g = lane >> 4;
  const int b = blockIdx.z, h = blockIdx.y, q0 = blockIdx.x * 128;
  const int bh = b * NHEAD + h;
  const int qg = q0 + wv * 16 + a15;
  constexpr int NT = TSEQ / 64;

  const bf16_t* Qh_b = Qhi + ((size_t)bh * TSEQ + qg) * HDIM;
  const bf16_t* Ql_b = Qlo + ((size_t)bh * TSEQ + qg) * HDIM;
  const bf16_t* Kh_b = Khi + (size_t)bh * TSEQ * HDIM;
  const bf16_t* Kl_b = Klo + (size_t)bh * TSEQ * HDIM;
  const bf16_t* Vh_b = Vth + (size_t)bh * HDIM * TSEQ;
  const bf16_t* Vl_b = Vtl + (size_t)bh * HDIM * TSEQ;
  const bf16_t* bmrow = BMt + ((size_t)b * TSEQ + qg) * TSEQ;

  bf16x8 qh[2], ql[2];
  qh[0] = *(const bf16x8*)&Qh_b[8 * g];
  qh[1] = *(const bf16x8*)&Qh_b[32 + 8 * g];
  ql[0] = *(const bf16x8*)&Ql_b[8 * g];
  ql[1] = *(const bf16x8*)&Ql_b[32 + 8 * g];

  f32x4 aco[4] = {};
  float m_run = -3.0e38f, l_run = 0.f;   // l_run is LANE-LOCAL now (reduced at end)
  bf16x4 bmv[4], bmn[4];

  const int ts = wv >> 1, ks = wv & 1;
  auto stage = [&](int k0, int buf) {
    size_t ko = (size_t)(k0 + 16 * ts + a15) * HDIM + 32 * ks + 8 * g;
    gload16(Kh_b + ko, &KH[buf][wv * 512]);
    gload16(Kl_b + ko, &KL[buf][wv * 512]);
    size_t vo = (size_t)(16 * ts + a15) * TSEQ + k0 + 32 * ks + 8 * g;
    gload16(Vh_b + vo, &VH[buf][wv * 512]);
    gload16(Vl_b + vo, &VL[buf][wv * 512]);
  };

#pragma unroll
  for (int mt = 0; mt < 4; ++mt) bmv[mt] = *(const bf16x4*)&bmrow[16 * mt + 4 * g];
  stage(0, 0);

  const int psb = wv * 512 + a15 * 32;
  const int r3 = a15 & 3;

  for (int t = 0; t < NT; ++t) {
    const int cur = t & 1;
    if (t + 1 < NT) {
      const int kn = (t + 1) * 64;
#pragma unroll
      for (int mt = 0; mt < 4; ++mt) bmn[mt] = *(const bf16x4*)&bmrow[kn + 16 * mt + 4 * g];
      stage(kn, cur ^ 1);
      asm volatile("s_waitcnt vmcnt(8)" ::: "memory");
    } else {
      asm volatile("s_waitcnt vmcnt(0)" ::: "memory");
    }
    SCHED0();
    SBAR();

    f32x4 s4[4];
    __builtin_amdgcn_s_setprio(1);
#pragma unroll
    for (int mt = 0; mt < 4; ++mt) {
      bf16x8 k0h = *(const bf16x8*)&KH[cur][(mt * 2 + 0) * 512 + lane * 8];
      bf16x8 k1h = *(const bf16x8*)&KH[cur][(mt * 2 + 1) * 512 + lane * 8];
      bf16x8 k0l = *(const bf16x8*)&KL[cur][(mt * 2 + 0) * 512 + lane * 8];
      bf16x8 k1l = *(const bf16x8*)&KL[cur][(mt * 2 + 1) * 512 + lane * 8];
      f32x4 sa = {};
      sa = mfma16(k0h, qh[0], sa);
      sa = mfma16(k1h, qh[1], sa);
      sa = mfma16(k0h, ql[0], sa);
      sa = mfma16(k1h, ql[1], sa);
      sa = mfma16(k0l, qh[0], sa);
      sa = mfma16(k1l, qh[1], sa);
      s4[mt] = sa;
    }
    __builtin_amdgcn_s_setprio(0);

#pragma unroll
    for (int mt = 0; mt < 4; ++mt)
#pragma unroll
      for (int r = 0; r < 4; ++r)
        s4[mt][r] = fmaf(s4[mt][r], 0.125f, (float)bmv[mt][r]);

    float tmax = -3.0e38f;
#pragma unroll
    for (int mt = 0; mt < 4; ++mt)
#pragma unroll
      for (int r = 0; r < 4; ++r) tmax = fmaxf(tmax, s4[mt][r]);
    tmax = fmaxf(tmax, __shfl_xor(tmax, 16));
    tmax = fmaxf(tmax, __shfl_xor(tmax, 32));
    if (!__all(tmax - m_run <= 8.0f)) {
      float mnew = fmaxf(m_run, tmax);
      float corr = __expf(m_run - mnew);   // lane-uniform
      l_run *= corr;
#pragma unroll
      for (int dt = 0; dt < 4; ++dt) aco[dt] *= corr;
      m_run = mnew;
    }
    float psum = 0.f;
    unsigned pk01[4], pk23[4];
#pragma unroll
    for (int mt = 0; mt < 4; ++mt) {
      float p0 = __expf(s4[mt][0] - m_run);
      float p1 = __expf(s4[mt][1] - m_run);
      float p2 = __expf(s4[mt][2] - m_run);
      float p3 = __expf(s4[mt][3] - m_run);
      psum += (p0 + p1) + (p2 + p3);
      pk01[mt] = pk2(p0, p1);
      pk23[mt] = pk2(p2, p3);
    }
    l_run += psum;                         // lane-local; cross-lane reduce at end

    __builtin_amdgcn_s_setprio(1);
#pragma unroll
    for (int kss = 0; kss < 2; ++kss) {
#pragma unroll
      for (int mh = 0; mh < 2; ++mh) {
        int mt = kss * 2 + mh;
        int phys = ((mh << 1) | (g >> 1)) ^ r3;
        uint2 w2;
        w2.x = pk01[mt];
        w2.y = pk23[mt];
        *(uint2*)&PS[psb + phys * 8 + (g & 1) * 4] = w2;
      }
      LGKM0();
      bf16x8 pf = *(const bf16x8*)&PS[psb + ((g ^ r3) << 3)];
#pragma unroll
      for (int dt = 0; dt < 4; ++dt) {
        bf16x8 vh = *(const bf16x8*)&VH[cur][(dt * 2 + kss) * 512 + lane * 8];
        bf16x8 vl = *(const bf16x8*)&VL[cur][(dt * 2 + kss) * 512 + lane * 8];
        aco[dt] = mfma16(vh, pf, aco[dt]);
        aco[dt] = mfma16(vl, pf, aco[dt]);
      }
    }
    __builtin_amdgcn_s_setprio(0);

    if (t + 1 < NT) {
#pragma unroll
      for (int mt = 0; mt < 4; ++mt) bmv[mt] = bmn[mt];
    }
    SBAR();
  }

  // final l reduction (was per-tile: 2 shfl x 32 tiles -> now 2 shfl once)
  l_run += __shfl_xor(l_run, 16);
  l_run += __shfl_xor(l_run, 32);

  float inv = 1.0f / l_run;
#pragma unroll
  for (int dt = 0; dt < 4; ++dt) {
    f32x4 o = aco[dt] * inv;
    bf16x4 oh, ol;
#pragma unroll
    for (int r = 0; r < 4; ++r) {
      __bf16 hb = (__bf16)o[r];
      oh[r] = hb;
      ol[r] = (__bf16)(o[r] - (float)hb);
    }
    size_t off = ((size_t)b * TSEQ + qg) * DMODEL + h * HDIM + dt * 16 + 4 * g;
    *(bf16x4*)&Oh[off] = oh;
    *(bf16x4*)&Ol[off] = ol;
  }
}

extern "C" void kernel_launch(void* const* d_in, const int* in_sizes, int n_in,
                              void* d_out, int out_size, void* d_ws, size_t ws_size,
                              hipStream_t stream) {
  const float* query = (const float*)d_in[0];
  const float* key = (const float*)d_in[1];
  const float* value = (const float*)d_in[2];
  const unsigned char* kpm = (const unsigned char*)d_in[3];
  const float* amask = (const float*)d_in[4];
  const float* sf = (const float*)d_in[5];
  const float* Wq = (const float*)d_in[6];
  const float* bq = (const float*)d_in[7];
  const float* Wk = (const float*)d_in[8];
  const float* bk = (const float*)d_in[9];
  const float* Wv = (const float*)d_in[10];
  const float* bv = (const float*)d_in[11];
  const float* Wo = (const float*)d_in[12];
  const float* bo = (const float*)d_in[13];
  const float* alpha = (const float*)d_in[14];
  float* out = (float*)d_out;

  const size_t NEL = (size_t)2 * NHEAD * TSEQ * HDIM;
  bf16_t* p = (bf16_t*)d_ws;
  bf16_t* Qh = p;                 // outbase for fused QKV: [Qh Ql Kh Kl Vh Vl]
  bf16_t* Ql = p + NEL;
  bf16_t* Kh = p + 2 * NEL;
  bf16_t* Kl = p + 3 * NEL;
  bf16_t* Vh = p + 4 * NEL;
  bf16_t* Vl = p + 5 * NEL;
  bf16_t* Oh = p + 6 * NEL;
  bf16_t* Ol = p + 7 * NEL;
  bf16_t* BMt = p + 8 * NEL;
  bf16_t* wsp = p + 10 * NEL;     // [wq hi/lo, wk hi/lo, wv hi/lo, wo hi/lo]
  bf16_t* woh = wsp + 6 * WEL, *wol = wsp + 7 * WEL;

  presplit_w<<<dim3(WEL / (256 * 8), 4), dim3(256), 0, stream>>>(Wq, Wk, Wv, Wo, wsp);
  build_bias<<<dim3(4096), dim3(256), 0, stream>>>(amask, kpm, sf, alpha, BMt);

  dim3 gb(512);
  dim3 gq(16, 32, 3);   // 1536 blocks: Q/K/V fused in one launch
  gemm_qkv_fused<<<gq, gb, 0, stream>>>(query, key, value, wsp, bq, bk, bv, p);

  dim3 ga(TSEQ / 128, NHEAD, 2);
  attn_mfma<<<ga, gb, 0, stream>>>(Qh, Ql, Kh, Kl, Vh, Vl, BMt, Oh, Ol);

  dim3 gg(16, 32);
  gemm_out<<<gg, gb, 0, stream>>>(Oh, Ol, woh, wol, bo, out);
}